// Round 1
// baseline (690.231 us; speedup 1.0000x reference)
//
#include <hip/hip_runtime.h>
#include <math.h>

// Problem constants (from reference): B=256, C=512, D=1024, K=16
#define NB 256
#define NC 512
#define ND 1024
#define NK 16

// ---------------------------------------------------------------------------
// Kernel 1: energy[b,c] = dot(inputs[b,c,:], W[0,:])
//   (bias skipped: it shifts all energies equally; softmax skipped: monotone.
//    Neither affects top-k indices, and the output is a pure gather.)
// One wave (64 lanes) per row; 4 waves per 256-thread block.
// Each lane: 4x float4 loads (lane-contiguous, 1 KiB per wave per instr).
// ---------------------------------------------------------------------------
__global__ __launch_bounds__(256) void energy_kernel(
    const float4* __restrict__ in,   // [B*C, D/4]
    const float4* __restrict__ W,    // [D/4]
    float* __restrict__ energy)      // [B*C]
{
    const int row  = blockIdx.x * 4 + (threadIdx.x >> 6);   // (b*C + c)
    const int lane = threadIdx.x & 63;

    const float4* r = in + (size_t)row * (ND / 4);

    float acc = 0.f;
#pragma unroll
    for (int j = 0; j < 4; ++j) {
        float4 a = r[lane + j * 64];
        float4 w = W[lane + j * 64];      // 4 KiB total -> L1-resident
        acc += a.x * w.x + a.y * w.y + a.z * w.z + a.w * w.w;
    }

    // wave-64 sum reduction
#pragma unroll
    for (int off = 32; off; off >>= 1)
        acc += __shfl_down(acc, off, 64);

    if (lane == 0) energy[row] = acc;
}

// ---------------------------------------------------------------------------
// Kernel 2: per batch b — top-16 argmax over energy[b, 0..511] (descending,
// ties -> smaller index, matching jax.lax.top_k stability), then gather
// out[b,k,:] = in[b, idx_k, :] with float4 copies.
// One 256-thread block per b.
// ---------------------------------------------------------------------------
__global__ __launch_bounds__(256) void topk_gather_kernel(
    const float* __restrict__ energy,  // [B, C]
    const float4* __restrict__ in,     // [B*C, D/4]
    float4* __restrict__ out)          // [B*K, D/4]
{
    const int b   = blockIdx.x;
    const int tid = threadIdx.x;

    __shared__ float e[NC];
    __shared__ int   topidx[NK];
    __shared__ float wv[4];
    __shared__ int   wi[4];

    e[tid]       = energy[b * NC + tid];
    e[tid + 256] = energy[b * NC + tid + 256];
    __syncthreads();

    for (int k = 0; k < NK; ++k) {
        // each thread: best of its two slots (tie -> smaller index)
        float v0 = e[tid], v1 = e[tid + 256];
        float bv;
        int   bi;
        if (v1 > v0) { bv = v1; bi = tid + 256; }
        else         { bv = v0; bi = tid; }

        // wave-64 arg-max reduce (tie -> smaller index)
#pragma unroll
        for (int off = 32; off; off >>= 1) {
            float ov = __shfl_down(bv, off, 64);
            int   oi = __shfl_down(bi, off, 64);
            if (ov > bv || (ov == bv && oi < bi)) { bv = ov; bi = oi; }
        }

        const int lane = tid & 63;
        const int w    = tid >> 6;
        if (lane == 0) { wv[w] = bv; wi[w] = bi; }
        __syncthreads();

        if (tid == 0) {
            float fv = wv[0];
            int   fi = wi[0];
#pragma unroll
            for (int j = 1; j < 4; ++j)
                if (wv[j] > fv || (wv[j] == fv && wi[j] < fi)) { fv = wv[j]; fi = wi[j]; }
            topidx[k] = fi;
            e[fi] = -INFINITY;   // remove winner
        }
        __syncthreads();
    }

    // gather: 16 rows x 1024 floats; 256 threads -> one float4 each per row
#pragma unroll 4
    for (int k = 0; k < NK; ++k) {
        const int c = topidx[k];
        const float4* src = in  + ((size_t)b * NC + c) * (ND / 4);
        float4*       dst = out + ((size_t)b * NK + k) * (ND / 4);
        dst[tid] = src[tid];
    }
}

// ---------------------------------------------------------------------------
extern "C" void kernel_launch(void* const* d_in, const int* in_sizes, int n_in,
                              void* d_out, int out_size, void* d_ws, size_t ws_size,
                              hipStream_t stream)
{
    const float* in = (const float*)d_in[0];   // [B, C, D] f32
    const float* W  = (const float*)d_in[1];   // [1, D]   f32
    // d_in[2] = bias (irrelevant to top-k), d_in[3] = topk scalar (compile-time)

    float* out    = (float*)d_out;             // [B, K, D] f32
    float* energy = (float*)d_ws;              // needs B*C*4 = 512 KiB scratch

    energy_kernel<<<NB * NC / 4, 256, 0, stream>>>(
        (const float4*)in, (const float4*)W, energy);

    topk_gather_kernel<<<NB, 256, 0, stream>>>(
        energy, (const float4*)in, (float4*)out);
}

// Round 7
// 685.539 us; speedup vs baseline: 1.0068x; 1.0068x over previous
//
#include <hip/hip_runtime.h>
#include <math.h>

// Problem constants (from reference): B=256, C=512, D=1024, K=16
#define NB 256
#define NC 512
#define ND 1024
#define NK 16

// ---------------------------------------------------------------------------
// Fused kernel: one 1024-thread block (16 waves) per batch b.
//   Phase 1: energy[c] = dot(inputs[b,c,:], W)  -> LDS   (wave w: rows w*32..+31)
//   Phase 2: wave 0 does top-16 argmax (desc, ties -> smaller idx, matching
//            jax.lax.top_k) fully in registers (8 energies per lane).
//   Phase 3: all threads gather the 16 selected rows (float4, L3-hot since
//            this block just streamed its own 2 MiB batch).
// Softmax/bias skipped: softmax is monotone in energy, bias is a uniform
// shift -> identical top-k indices; output is a bit-exact gather.
// ---------------------------------------------------------------------------
__global__ __launch_bounds__(1024) void EnergyAttention_fused_kernel(
    const float4* __restrict__ in,   // [B*C, D/4]
    const float4* __restrict__ W4,   // [D/4]
    float4* __restrict__ out)        // [B*K, D/4]
{
    const int b    = blockIdx.x;
    const int tid  = threadIdx.x;
    const int wave = tid >> 6;       // 0..15
    const int lane = tid & 63;

    __shared__ float e[NC];
    __shared__ int   topidx[NK];

    // W fragments: 4 KiB total, each lane keeps its 4 float4s in registers
    const float4 w0 = W4[lane];
    const float4 w1 = W4[lane + 64];
    const float4 w2 = W4[lane + 128];
    const float4 w3 = W4[lane + 192];

    const float4* base = in + (size_t)b * NC * (ND / 4);

    // ---- Phase 1: energies (2 rows per iter for ILP: 8 loads in flight) ----
    for (int r = 0; r < 32; r += 2) {
        const int c0 = wave * 32 + r;
        const float4* r0 = base + (size_t)c0 * (ND / 4);
        const float4* r1 = r0 + (ND / 4);

        float4 a0 = r0[lane], b0 = r0[lane + 64], c0v = r0[lane + 128], d0 = r0[lane + 192];
        float4 a1 = r1[lane], b1 = r1[lane + 64], c1v = r1[lane + 128], d1 = r1[lane + 192];

        // same per-fragment grouping/order as the validated kernel
        float acc0 = 0.f, acc1 = 0.f;
        acc0 += a0.x * w0.x + a0.y * w0.y + a0.z * w0.z + a0.w * w0.w;
        acc0 += b0.x * w1.x + b0.y * w1.y + b0.z * w1.z + b0.w * w1.w;
        acc0 += c0v.x * w2.x + c0v.y * w2.y + c0v.z * w2.z + c0v.w * w2.w;
        acc0 += d0.x * w3.x + d0.y * w3.y + d0.z * w3.z + d0.w * w3.w;

        acc1 += a1.x * w0.x + a1.y * w0.y + a1.z * w0.z + a1.w * w0.w;
        acc1 += b1.x * w1.x + b1.y * w1.y + b1.z * w1.z + b1.w * w1.w;
        acc1 += c1v.x * w2.x + c1v.y * w2.y + c1v.z * w2.z + c1v.w * w2.w;
        acc1 += d1.x * w3.x + d1.y * w3.y + d1.z * w3.z + d1.w * w3.w;

#pragma unroll
        for (int off = 32; off; off >>= 1) {
            acc0 += __shfl_down(acc0, off, 64);
            acc1 += __shfl_down(acc1, off, 64);
        }
        if (lane == 0) { e[c0] = acc0; e[c0 + 1] = acc1; }
    }
    __syncthreads();

    // ---- Phase 2: wave 0 selects top-16 (in-register, static indexing) ----
    if (wave == 0) {
        const int idxbase = lane * 8;
        float v[8];
#pragma unroll
        for (int j = 0; j < 8; ++j) v[j] = e[idxbase + j];

        for (int k = 0; k < NK; ++k) {
            // lane-local argmax over 8 (strict '>' keeps smallest j on ties)
            float bv = v[0];
            int   bj = 0;
#pragma unroll
            for (int j = 1; j < 8; ++j)
                if (v[j] > bv) { bv = v[j]; bj = j; }
            int bi = idxbase + bj;

            // wave-64 arg-max reduce (tie -> smaller index)
#pragma unroll
            for (int off = 32; off; off >>= 1) {
                float ov = __shfl_down(bv, off, 64);
                int   oi = __shfl_down(bi, off, 64);
                if (ov > bv || (ov == bv && oi < bi)) { bv = ov; bi = oi; }
            }

            const int win = __shfl(bi, 0, 64);   // broadcast winner
            if (lane == 0) topidx[k] = win;

            // clear winner slot (static indices only — no scratch)
#pragma unroll
            for (int j = 0; j < 8; ++j)
                if (win == idxbase + j) v[j] = -INFINITY;
        }
    }
    __syncthreads();

    // ---- Phase 3: gather 16 rows x 256 float4; 4 rows concurrently ----
    const int g = tid >> 8;     // row-group 0..3
    const int t = tid & 255;    // float4 column
#pragma unroll
    for (int k = 0; k < NK / 4; ++k) {
        const int kk = k * 4 + g;
        const int c  = topidx[kk];
        out[((size_t)b * NK + kk) * (ND / 4) + t] = base[(size_t)c * (ND / 4) + t];
    }
}

// ---------------------------------------------------------------------------
extern "C" void kernel_launch(void* const* d_in, const int* in_sizes, int n_in,
                              void* d_out, int out_size, void* d_ws, size_t ws_size,
                              hipStream_t stream)
{
    const float* in = (const float*)d_in[0];   // [B, C, D] f32
    const float* W  = (const float*)d_in[1];   // [1, D]   f32
    // d_in[2] = bias (uniform shift, irrelevant to top-k)
    // d_in[3] = topk scalar (compile-time NK)

    float* out = (float*)d_out;                // [B, K, D] f32

    EnergyAttention_fused_kernel<<<NB, 1024, 0, stream>>>(
        (const float4*)in, (const float4*)W, (float4*)out);
}